// Round 1
// 782.841 us; speedup vs baseline: 1.2789x; 1.2789x over previous
//
#include <hip/hip_runtime.h>
#include <math.h>

#define B_ 8
#define C_ 256
#define N_ 4096
#define K_ 1024
#define NH_ 8
#define HD_ 32

// float4-granular XOR swizzle inside a 64x256 f32 LDS tile: conflict-free ds_read_b128
#define SWZ(i,c) (((((c)>>2) ^ ((i)&15)) << 2) | ((c)&3))

// ---------------- Kernel 1: importance = sigmoid(W2·gelu(W1·x+b1)+b2) + 0.5*bmap ----------------
__global__ __launch_bounds__(256) void imp_kernel(
    const float* __restrict__ x, const float* __restrict__ bmap,
    const float* __restrict__ w1, const float* __restrict__ b1,
    const float* __restrict__ w2, const float* __restrict__ b2,
    float* __restrict__ imp_out)
{
  __shared__ float xs[64][256];   // 64 pixels x 256 channels, swizzled
  const int t = threadIdx.x;
  const int b = blockIdx.x >> 6, tile = blockIdx.x & 63;
  const int n0 = tile * 64;
  {
    const int cg = t >> 6, i = t & 63;
    const float* xb = x + (size_t)b*C_*N_ + n0 + i;
    #pragma unroll 4
    for (int cc = 0; cc < 64; cc++){
      int c = cc*4 + cg;
      xs[i][SWZ(i,c)] = xb[(size_t)c*N_];
    }
  }
  __syncthreads();
  const int i = t & 63, og = t >> 6;   // pixel i, hidden-output group og*16..+15
  float acc[16];
  #pragma unroll
  for (int oo=0;oo<16;oo++) acc[oo] = 0.f;
  for (int c8 = 0; c8 < 256; c8 += 8){
    float4 xa = *(const float4*)&xs[i][SWZ(i,c8)];
    float4 xc = *(const float4*)&xs[i][SWZ(i,c8+4)];
    #pragma unroll
    for (int oo=0;oo<16;oo++){
      const float* wr = w1 + (size_t)(og*16+oo)*C_ + c8;
      float4 wa = *(const float4*)wr;
      float4 wb = *(const float4*)(wr+4);
      acc[oo] += xa.x*wa.x + xa.y*wa.y + xa.z*wa.z + xa.w*wa.w
               + xc.x*wb.x + xc.y*wb.y + xc.z*wb.z + xc.w*wb.w;
    }
  }
  float p = 0.f;
  #pragma unroll
  for (int oo=0;oo<16;oo++){
    int o = og*16+oo;
    float a = acc[oo] + b1[o];
    float g = 0.5f*a*(1.f + erff(a*0.70710678118654752f));  // exact GELU
    p += w2[o]*g;
  }
  __syncthreads();
  float* red = &xs[0][0];   // reuse LDS after all reads done
  red[t] = p;
  __syncthreads();
  if (t < 64){
    float s = red[t]+red[t+64]+red[t+128]+red[t+192] + b2[0];
    float sig = 1.f/(1.f+expf(-s));
    imp_out[(size_t)b*N_ + n0 + t] = sig + 0.5f*bmap[(size_t)b*N_ + n0 + t];
  }
}

// ---------------- Kernel 2: exact top-K via bitonic sort of (value|~idx) keys ----------------
__global__ __launch_bounds__(1024) void topk_kernel(const float* __restrict__ imp, int* __restrict__ tidx)
{
  __shared__ unsigned long long s[4096];
  __shared__ int idx[1024];
  const int b = blockIdx.x, t = threadIdx.x;
  const float* ib = imp + (size_t)b*N_;
  for (int m = t; m < N_; m += 1024){
    unsigned u = __float_as_uint(ib[m]);
    u = (u & 0x80000000u) ? ~u : (u | 0x80000000u);        // order-preserving bits
    s[m] = ((unsigned long long)u << 32) | (unsigned)(~m); // tie -> lower index wins
  }
  for (int k = 2; k <= 4096; k <<= 1){
    for (int j = k >> 1; j > 0; j >>= 1){
      __syncthreads();
      #pragma unroll 2
      for (int m = t; m < 2048; m += 1024){
        int i = 2*m - (m & (j-1));
        int l = i + j;
        unsigned long long a = s[i], c = s[l];
        if ((a > c) == ((i & k) == 0)){ s[i] = c; s[l] = a; }
      }
    }
  }
  __syncthreads();
  idx[t] = (int)(~(unsigned)(s[3072 + t]));   // largest 1024 keys -> indices
  // sort selected indices ascending (order is irrelevant to the math; improves locality)
  for (int k = 2; k <= 1024; k <<= 1){
    for (int j = k >> 1; j > 0; j >>= 1){
      __syncthreads();
      if (t < 512){
        int i = 2*t - (t & (j-1));
        int l = i + j;
        int a = idx[i], c = idx[l];
        if ((a > c) == ((i & k) == 0)){ idx[i] = c; idx[l] = a; }
      }
    }
  }
  __syncthreads();
  tidx[(size_t)b*K_ + t] = idx[t];
}

// ---------------- GEMM helper: one weight set, 32 outputs per thread (2 chunks of 16) ----------------
__device__ __forceinline__ void gemm32(const float xs[64][256], int i, int o_base,
    const float* __restrict__ wset, const float* __restrict__ bset,
    float* __restrict__ orow)
{
  #pragma unroll 1
  for (int och = 0; och < 2; och++){
    const int o0 = o_base + och*16;
    float acc[16];
    #pragma unroll
    for (int oo=0;oo<16;oo++) acc[oo]=0.f;
    for (int c8 = 0; c8 < 256; c8 += 8){
      float4 xa = *(const float4*)&xs[i][SWZ(i,c8)];
      float4 xc = *(const float4*)&xs[i][SWZ(i,c8+4)];
      #pragma unroll
      for (int oo=0;oo<16;oo++){
        const float* wr = wset + (size_t)(o0+oo)*C_ + c8;
        float4 wa = *(const float4*)wr;
        float4 wb = *(const float4*)(wr+4);
        acc[oo] += xa.x*wa.x + xa.y*wa.y + xa.z*wa.z + xa.w*wa.w
                 + xc.x*wb.x + xc.y*wb.y + xc.z*wb.z + xc.w*wb.w;
      }
    }
    #pragma unroll
    for (int oo=0;oo<16;oo+=4){
      float4 v;
      v.x = acc[oo+0] + bset[o0+oo+0];
      v.y = acc[oo+1] + bset[o0+oo+1];
      v.z = acc[oo+2] + bset[o0+oo+2];
      v.w = acc[oo+3] + bset[o0+oo+3];
      *(float4*)(orow + o0 + oo) = v;
    }
  }
}

// ---------------- Kernel 3: gather x_sp + one of Q/K/V projections per block ----------------
// grid = (ktile=16, set=3, b=8), 512 threads = 8 waves; og = t>>6 stays wave-uniform so
// weight loads remain single-transaction L1 broadcasts. 3072 waves total (~3/SIMD) vs 512 before.
__global__ __launch_bounds__(512) void qkv_kernel(
    const float* __restrict__ x, const int* __restrict__ tidx,
    const float* __restrict__ wq, const float* __restrict__ bq,
    const float* __restrict__ wk, const float* __restrict__ bk,
    const float* __restrict__ wv, const float* __restrict__ bv,
    float* __restrict__ xsp, float* __restrict__ qb, float* __restrict__ kb, float* __restrict__ vb)
{
  __shared__ float xs[64][256];
  const int t = threadIdx.x;
  const int kt  = blockIdx.x;        // 16 k-tiles of 64 tokens
  const int set = blockIdx.y;        // 0=q, 1=k, 2=v
  const int b   = blockIdx.z;
  const int k0  = kt * 64;
  {
    const int i = t & 63, cg = t >> 6;   // row i, channel group cg*32..+31
    const int n = tidx[(size_t)b*K_ + k0 + i];
    const float* xb = x + (size_t)b*C_*N_ + n;
    #pragma unroll 4
    for (int cc = 0; cc < 32; cc++){
      int c = cg*32 + cc;
      xs[i][SWZ(i,c)] = xb[(size_t)c*N_];
    }
  }
  __syncthreads();
  if (set == 0){                       // write gathered tile out once (q-block only)
    float* xspb = xsp + ((size_t)b*K_ + k0)*C_;
    for (int e = t; e < 64*256; e += 512){
      int it = e >> 8, c = e & 255;
      xspb[e] = xs[it][SWZ(it,c)];
    }
  }
  const float* wset = set==0 ? wq : set==1 ? wk : wv;
  const float* bset = set==0 ? bq : set==1 ? bk : bv;
  float*       outp = set==0 ? qb : set==1 ? kb : vb;
  const int i = t & 63, og = t >> 6;   // og 0..7, wave-uniform
  const size_t row = ((size_t)b*K_ + k0 + i)*C_;
  gemm32(xs, i, og*32, wset, bset, outp + row);
}

// ---------------- Kernel 4: flash-style attention, 1 q-row per lane ----------------
__global__ __launch_bounds__(64) void attn_kernel(
    const float* __restrict__ qb, const float* __restrict__ kb,
    const float* __restrict__ vb, float* __restrict__ ob)
{
  __shared__ float Ks[64][36], Vs[64][36], ps[64][65];
  const int t = threadIdx.x;
  const int qt = blockIdx.x, h = blockIdx.y, b = blockIdx.z;
  const float* qrow = qb + (((size_t)b*K_) + qt*64 + t)*C_ + h*HD_;
  float q[32], o[32];
  #pragma unroll
  for (int d = 0; d < 32; d += 4){
    float4 v = *(const float4*)(qrow + d);
    q[d]=v.x; q[d+1]=v.y; q[d+2]=v.z; q[d+3]=v.w;
  }
  #pragma unroll
  for (int d = 0; d < 32; d++) o[d] = 0.f;
  float mrun = -3.0e38f, lrun = 0.f;
  for (int kt = 0; kt < 16; kt++){
    __syncthreads();
    for (int e = t; e < 2048; e += 64){
      int r = e >> 5, d = e & 31;
      size_t base = (((size_t)b*K_) + kt*64 + r)*C_ + h*HD_ + d;
      Ks[r][d] = kb[base];
      Vs[r][d] = vb[base];
    }
    __syncthreads();
    float tmax = mrun;
    for (int j = 0; j < 64; j++){
      float s = 0.f;
      #pragma unroll
      for (int d = 0; d < 32; d++) s += q[d]*Ks[j][d];
      s *= 0.17677669529663688f;  // 1/sqrt(32)
      ps[t][j] = s;
      tmax = fmaxf(tmax, s);
    }
    float alpha = __expf(mrun - tmax);
    float lsum = 0.f;
    #pragma unroll
    for (int d = 0; d < 32; d++) o[d] *= alpha;
    for (int j = 0; j < 64; j++){
      float p = __expf(ps[t][j] - tmax);
      lsum += p;
      #pragma unroll
      for (int d = 0; d < 32; d++) o[d] += p*Vs[j][d];
    }
    lrun = lrun*alpha + lsum;
    mrun = tmax;
  }
  const float inv = 1.f/lrun;
  float* orow = ob + (((size_t)b*K_) + qt*64 + t)*C_ + h*HD_;
  #pragma unroll
  for (int d = 0; d < 32; d += 4){
    float4 v;
    v.x = o[d]*inv; v.y = o[d+1]*inv; v.z = o[d+2]*inv; v.w = o[d+3]*inv;
    *(float4*)(orow + d) = v;
  }
}

// ---------------- Kernel 5: out-proj + residual + LayerNorm + scatter into out ----------------
__global__ __launch_bounds__(256) void out_kernel(
    const float* __restrict__ ob, const float* __restrict__ xsp,
    const int* __restrict__ tidx, const float* __restrict__ wo, const float* __restrict__ bo,
    const float* __restrict__ lng, const float* __restrict__ lnb,
    float* __restrict__ out)
{
  __shared__ float os[64][256];
  const int t = threadIdx.x;
  const int b = blockIdx.x >> 4, k0 = (blockIdx.x & 15)*64;
  const float* obase = ob + ((size_t)b*K_ + k0)*C_;
  for (int it = 0; it < 64; it++)
    os[it][SWZ(it, t)] = obase[it*256 + t];
  __syncthreads();
  const int i = t & 63, og = t >> 6;
  float y[64];
  #pragma unroll 1
  for (int och = 0; och < 4; och++){
    const int o0 = og*64 + och*16;
    float acc[16];
    #pragma unroll
    for (int oo=0;oo<16;oo++) acc[oo]=0.f;
    for (int c8 = 0; c8 < 256; c8 += 8){
      float4 xa = *(const float4*)&os[i][SWZ(i,c8)];
      float4 xc = *(const float4*)&os[i][SWZ(i,c8+4)];
      #pragma unroll
      for (int oo=0;oo<16;oo++){
        const float* wr = wo + (size_t)(o0+oo)*C_ + c8;
        float4 wa = *(const float4*)wr;
        float4 wb = *(const float4*)(wr+4);
        acc[oo] += xa.x*wa.x + xa.y*wa.y + xa.z*wa.z + xa.w*wa.w
                 + xc.x*wb.x + xc.y*wb.y + xc.z*wb.z + xc.w*wb.w;
      }
    }
    const float* xr = xsp + ((size_t)b*K_ + k0 + i)*C_ + o0;
    #pragma unroll
    for (int oo=0;oo<16;oo+=4){
      float4 xv = *(const float4*)(xr + oo);
      y[och*16+oo+0] = acc[oo+0] + bo[o0+oo+0] + xv.x;
      y[och*16+oo+1] = acc[oo+1] + bo[o0+oo+1] + xv.y;
      y[och*16+oo+2] = acc[oo+2] + bo[o0+oo+2] + xv.z;
      y[och*16+oo+3] = acc[oo+3] + bo[o0+oo+3] + xv.w;
    }
  }
  float s1 = 0.f, s2 = 0.f;
  #pragma unroll
  for (int m2 = 0; m2 < 64; m2++){ s1 += y[m2]; s2 += y[m2]*y[m2]; }
  __syncthreads();
  float* red = &os[0][0];   // reuse LDS
  red[t] = s1;
  red[256 + t] = s2;
  __syncthreads();
  if (t < 64){
    float a  = red[t]+red[t+64]+red[t+128]+red[t+192];
    float q2 = red[256+t]+red[320+t]+red[384+t]+red[448+t];
    float mu = a*(1.f/256.f);
    float var = q2*(1.f/256.f) - mu*mu;
    red[512+t] = mu;
    red[576+t] = rsqrtf(var + 1e-5f);
  }
  __syncthreads();
  const float mu = red[512+i], rs = red[576+i];
  const int n = tidx[(size_t)b*K_ + k0 + i];
  float* outb = out + (size_t)b*C_*N_ + n;
  #pragma unroll
  for (int m2 = 0; m2 < 64; m2++){
    int o = og*64 + m2;
    outb[(size_t)o*N_] = (y[m2]-mu)*rs*lng[o] + lnb[o];
  }
}

extern "C" void kernel_launch(void* const* d_in, const int* in_sizes, int n_in,
                              void* d_out, int out_size, void* d_ws, size_t ws_size,
                              hipStream_t stream)
{
  const float* x    = (const float*)d_in[0];
  const float* bmap = (const float*)d_in[1];
  const float* w1   = (const float*)d_in[2];
  const float* b1   = (const float*)d_in[3];
  const float* w2   = (const float*)d_in[4];
  const float* b2   = (const float*)d_in[5];
  const float* wq   = (const float*)d_in[6];
  const float* bq   = (const float*)d_in[7];
  const float* wk   = (const float*)d_in[8];
  const float* bk   = (const float*)d_in[9];
  const float* wv   = (const float*)d_in[10];
  const float* bv   = (const float*)d_in[11];
  const float* wo   = (const float*)d_in[12];
  const float* bo   = (const float*)d_in[13];
  const float* lng  = (const float*)d_in[14];
  const float* lnb  = (const float*)d_in[15];

  float* out = (float*)d_out;
  float* imp_out = out + (size_t)B_*C_*N_;   // importance is output #2, concatenated

  char* wsb = (char*)d_ws;
  int*   tidx = (int*)wsb;                       // 32 KB (padded to 64 KB)
  float* xsp  = (float*)(wsb + 65536);           // [B,K,C] 8 MB
  float* qb   = xsp + (size_t)B_*K_*C_;
  float* kb   = qb  + (size_t)B_*K_*C_;
  float* vb   = kb  + (size_t)B_*K_*C_;
  float* obuf = vb  + (size_t)B_*K_*C_;

  hipMemcpyAsync(out, x, (size_t)B_*C_*N_*sizeof(float), hipMemcpyDeviceToDevice, stream);
  imp_kernel <<<dim3(512),       dim3(256),  0, stream>>>(x, bmap, w1, b1, w2, b2, imp_out);
  topk_kernel<<<dim3(8),         dim3(1024), 0, stream>>>(imp_out, tidx);
  qkv_kernel <<<dim3(16, 3, 8),  dim3(512),  0, stream>>>(x, tidx, wq, bq, wk, bk, wv, bv, xsp, qb, kb, vb);
  attn_kernel<<<dim3(16, 8, 8),  dim3(64),   0, stream>>>(qb, kb, vb, obuf);
  out_kernel <<<dim3(128),       dim3(256),  0, stream>>>(obuf, xsp, tidx, wo, bo, lng, lnb, out);
}